// Round 10
// baseline (369.162 us; speedup 1.0000x reference)
//
#include <hip/hip_runtime.h>

typedef short bf16x8 __attribute__((ext_vector_type(8)));
typedef float f32x16 __attribute__((ext_vector_type(16)));
typedef float f32x2  __attribute__((ext_vector_type(2)));

#define NBGROUPS 128         // grid = 128 x 16; 64 tiles/block, 8 pair-iters/wave
#define SCALE 4.7746482927568601f   // 30/(2*pi): weights pre-scaled -> args in revolutions

union Frag { bf16x8 v; unsigned u[4]; uint4 q; };

__device__ __forceinline__ unsigned pk_bf16(float lo, float hi) {
    unsigned r;
    asm("v_cvt_pk_bf16_f32 %0, %1, %2" : "=v"(r) : "v"(lo), "v"(hi));
    return r;
}
__device__ __forceinline__ float lo_f(unsigned w) { return __uint_as_float(w << 16); }
__device__ __forceinline__ float hi_f(unsigned w) { return __uint_as_float(w & 0xffff0000u); }

// packed sin(2*pi*z): v = z - rndne(z) in [-0.5,0.5], deg-9 poly (max err ~6e-6)
__device__ __forceinline__ f32x2 sin2(f32x2 z) {
    f32x2 r  = { rintf(z.x), rintf(z.y) };
    f32x2 v  = z - r;
    f32x2 v2 = v * v;
    f32x2 p  = { 32.765379f, 32.765379f };
    p = __builtin_elementwise_fma(p, v2, (f32x2){-74.468884f, -74.468884f});
    p = __builtin_elementwise_fma(p, v2, (f32x2){ 81.365064f,  81.365064f});
    p = __builtin_elementwise_fma(p, v2, (f32x2){-41.331084f, -41.331084f});
    p = __builtin_elementwise_fma(p, v2, (f32x2){  6.2830526f,  6.2830526f});
    return p * v;
}

// Bias table: [ ((Lb*2+tg)*2 + hi)*4 + q ] float4, slots q*4..q*4+3 of acc[tg].
struct BiasRegs { f32x2 p[2][8]; };
__device__ __forceinline__ BiasRegs load_bias(const float4* ldsBias, int Lb, int hi) {
    BiasRegs br;
#pragma unroll
    for (int tg = 0; tg < 2; ++tg) {
        const float4* base = &ldsBias[((Lb*2+tg)*2 + hi)*4];
#pragma unroll
        for (int q = 0; q < 4; ++q) {
            float4 b = base[q];
            br.p[tg][2*q]   = (f32x2){b.x, b.y};
            br.p[tg][2*q+1] = (f32x2){b.z, b.w};
        }
    }
    return br;
}

// acc + bias -> sin -> hi/lo bf16 B-frags. Pair j in tg: slots (2j,2j+1) -> frag[tg*2+(j>>2)].u[j&3]
__device__ __forceinline__ void transitionHL(const f32x16* acc, const BiasRegs& br,
                                             Frag* Bhi, Frag* Blo) {
#pragma unroll
    for (int tg = 0; tg < 2; ++tg)
#pragma unroll
        for (int j = 0; j < 8; ++j) {
            f32x2 z = (f32x2){ acc[tg][2*j], acc[tg][2*j+1] } + br.p[tg][j];
            f32x2 s = sin2(z);
            unsigned ph = pk_bf16(s.x, s.y);
            f32x2 hf = { lo_f(ph), hi_f(ph) };
            f32x2 d  = s - hf;
            Bhi[tg*2 + (j>>2)].u[j&3] = ph;
            Blo[tg*2 + (j>>2)].u[j&3] = pk_bf16(d.x, d.y);
        }
}
// hi-only (feeds the uncompensated last hidden layer)
__device__ __forceinline__ void transitionH(const f32x16* acc, const BiasRegs& br, Frag* Bhi) {
#pragma unroll
    for (int tg = 0; tg < 2; ++tg)
#pragma unroll
        for (int j = 0; j < 8; ++j) {
            f32x2 z = (f32x2){ acc[tg][2*j], acc[tg][2*j+1] } + br.p[tg][j];
            f32x2 s = sin2(z);
            Bhi[tg*2 + (j>>2)].u[j&3] = pk_bf16(s.x, s.y);
        }
}

// one compensated mid-layer MFMA cluster for one tile (12 MFMAs), setprio-wrapped
__device__ __forceinline__ void layerHL(f32x16* acc, const Frag* Bhi, const Frag* Blo,
                                        const uint4* ldsAhi, const uint4* ldsAlo,
                                        int L, int lane, const f32x16& zero16) {
    __builtin_amdgcn_s_setprio(1);
#pragma unroll
    for (int c = 0; c < 4; ++c) {
        Frag Ah0, Ah1, Al0, Al1;
        Ah0.q = ldsAhi[((L*2+0)*4+c)*64 + lane];
        Ah1.q = ldsAhi[((L*2+1)*4+c)*64 + lane];
        Al0.q = ldsAlo[((L*2+0)*4+c)*64 + lane];
        Al1.q = ldsAlo[((L*2+1)*4+c)*64 + lane];
        acc[0] = __builtin_amdgcn_mfma_f32_32x32x16_bf16(Ah0.v, Bhi[c].v, (c==0)?zero16:acc[0], 0, 0, 0);
        acc[1] = __builtin_amdgcn_mfma_f32_32x32x16_bf16(Ah1.v, Bhi[c].v, (c==0)?zero16:acc[1], 0, 0, 0);
        acc[0] = __builtin_amdgcn_mfma_f32_32x32x16_bf16(Ah0.v, Blo[c].v, acc[0], 0, 0, 0);
        acc[1] = __builtin_amdgcn_mfma_f32_32x32x16_bf16(Ah1.v, Blo[c].v, acc[1], 0, 0, 0);
        acc[0] = __builtin_amdgcn_mfma_f32_32x32x16_bf16(Al0.v, Bhi[c].v, acc[0], 0, 0, 0);
        acc[1] = __builtin_amdgcn_mfma_f32_32x32x16_bf16(Al1.v, Bhi[c].v, acc[1], 0, 0, 0);
    }
    __builtin_amdgcn_s_setprio(0);
}
// hi-only last hidden layer (8 MFMAs)
__device__ __forceinline__ void layerH(f32x16* acc, const Frag* Bhi,
                                       const uint4* ldsAhi, int L, int lane,
                                       const f32x16& zero16) {
    __builtin_amdgcn_s_setprio(1);
#pragma unroll
    for (int c = 0; c < 4; ++c) {
        Frag Ah0, Ah1;
        Ah0.q = ldsAhi[((L*2+0)*4+c)*64 + lane];
        Ah1.q = ldsAhi[((L*2+1)*4+c)*64 + lane];
        acc[0] = __builtin_amdgcn_mfma_f32_32x32x16_bf16(Ah0.v, Bhi[c].v, (c==0)?zero16:acc[0], 0, 0, 0);
        acc[1] = __builtin_amdgcn_mfma_f32_32x32x16_bf16(Ah1.v, Bhi[c].v, (c==0)?zero16:acc[1], 0, 0, 0);
    }
    __builtin_amdgcn_s_setprio(0);
}

__global__ __launch_bounds__(256, 2)
void siren_kernel(const float* __restrict__ x, const float* __restrict__ W0m,
                  const float* __restrict__ b0, const float* __restrict__ Wm,
                  const float* __restrict__ bm, const float* __restrict__ Wl,
                  const float* __restrict__ bl, float* __restrict__ out)
{
    __shared__ uint4  ldsAhi[3*2*4*64];   // 24KB: hi frags, layers 0..2
    __shared__ uint4  ldsAlo[2*2*4*64];   // 16KB: lo frags, layers 0..1 only
    __shared__ float4 ldsBias[4*2*2*4];   // 1KB
    __shared__ float  ldsWl[2][32];       // 256B: Wl in acc-slot order per half

    const int tid  = threadIdx.x;
    const int pg   = blockIdx.x;          // point group (0..127) — fast dim
    const int o    = blockIdx.y;          // subnet (0..15)
    const int lane = tid & 63;
    const int wv   = tid >> 6;
    const int col  = lane & 31;
    const int hi   = lane >> 5;

    // ---- stage mid-layer weight fragments, hi/lo compensated, pre-scaled ----
    for (int idx = tid; idx < 3*2*4*64; idx += 256) {
        int l2  = idx & 63;
        int fi  = idx >> 6;
        int c   = fi & 3;
        int tg  = (fi >> 2) & 1;
        int L   = fi >> 3;
        int hi2 = l2 >> 5;
        int g   = tg*32 + (l2 & 31);
        int th  = c >> 1, s = c & 1;
        const float2* Wrow2 = (const float2*)(Wm + (((size_t)(L*16 + o)*64 + g)*64));
        uint4 whi, wlo;
        unsigned* uh = (unsigned*)&whi;
        unsigned* ul = (unsigned*)&wlo;
#pragma unroll
        for (int wi = 0; wi < 4; ++wi) {
            int h = th*32 + s*16 + 8*(wi>>1) + 2*(wi&1) + 4*hi2;   // even
            float2 wp = Wrow2[h >> 1];
            float a = SCALE*wp.x, b = SCALE*wp.y;
            unsigned ph = pk_bf16(a, b);
            uh[wi] = ph;
            ul[wi] = pk_bf16(a - lo_f(ph), b - hi_f(ph));
        }
        ldsAhi[idx] = whi;
        if (idx < 2*2*4*64) ldsAlo[idx] = wlo;   // lo only for L=0,1
    }
    // ---- stage biases (pre-scaled), contiguous per (Lb,tg,hi) ----
    if (tid < 64) {
        int q   = tid & 3;
        int hi2 = (tid >> 2) & 1;
        int tg  = (tid >> 3) & 1;
        int Lb  = tid >> 4;          // 0..2 mid, 3 = first layer
        int h0  = tg*32 + 8*q + 4*hi2;
        const float* bsrc = (Lb < 3) ? (bm + (Lb*16 + o)*64) : (b0 + o*64);
        ldsBias[tid] = make_float4(SCALE*bsrc[h0], SCALE*bsrc[h0+1],
                                   SCALE*bsrc[h0+2], SCALE*bsrc[h0+3]);
    }
    // ---- stage last-layer weights in acc-slot order: ldsWl[hi][tg*16+r] ----
    if (tid >= 64 && tid < 128) {
        int t2  = tid - 64;
        int hi2 = t2 >> 5;
        int idx = t2 & 31;
        int tg  = idx >> 4;
        int r   = idx & 15;
        int s = r >> 3, j = r & 7;
        int h = tg*32 + 16*s + (j & 3) + 8*(j >> 2) + 4*hi2;
        ldsWl[hi2][idx] = Wl[o*64 + h];
    }

    // ---- first-layer A frags, fully compensated ----
    Frag L1A[2];
#pragma unroll
    for (int tg = 0; tg < 2; ++tg) {
        int g = tg*32 + col;
        float2 wp = ((const float2*)W0m)[o*64 + g];
        float s0 = SCALE*wp.x, s1 = SCALE*wp.y;
        unsigned u0 = pk_bf16(s0, s0), u1 = pk_bf16(s1, s1);
        float l0 = s0 - lo_f(u0), l1 = s1 - lo_f(u1);
        L1A[tg].u[0] = hi ? 0u : u0;
        L1A[tg].u[1] = hi ? 0u : u1;
        L1A[tg].u[2] = hi ? 0u : pk_bf16(l0, l0);
        L1A[tg].u[3] = hi ? 0u : pk_bf16(l1, l1);
    }
    const float blv = bl[o] + 0.5f;

    // persistent zero accumulator: C-operand for each chain's first MFMA
    f32x16 zero16;
#pragma unroll
    for (int i = 0; i < 16; ++i) zero16[i] = 0.f;

    __syncthreads();

    const int tbase = pg*64 + wv;
#pragma unroll 1
    for (int k = 0; k < 8; ++k) {
        const int ta  = tbase + 8*k;
        const int ppa = ta*32 + col;
        const int ppb = ppa + 128;       // tile tb = ta + 4

        // ---- first layer inputs, both tiles ----
        float2 xa = ((const float2*)x)[ppa];
        float2 xb = ((const float2*)x)[ppb];
        Frag B1a, B1b;
        {
            unsigned ux = pk_bf16(xa.x, xa.y);
            float x0h = lo_f(ux), x1h = hi_f(ux);
            unsigned w0 = pk_bf16(x0h, xa.x - x0h);
            unsigned w1 = pk_bf16(x1h, xa.y - x1h);
            B1a.u[0] = hi ? 0u : w0;  B1a.u[1] = hi ? 0u : w1;
            B1a.u[2] = hi ? 0u : w0;  B1a.u[3] = hi ? 0u : w1;
            ux = pk_bf16(xb.x, xb.y);
            x0h = lo_f(ux); x1h = hi_f(ux);
            w0 = pk_bf16(x0h, xb.x - x0h);
            w1 = pk_bf16(x1h, xb.y - x1h);
            B1b.u[0] = hi ? 0u : w0;  B1b.u[1] = hi ? 0u : w1;
            B1b.u[2] = hi ? 0u : w0;  B1b.u[3] = hi ? 0u : w1;
        }

        BiasRegs br3 = load_bias(ldsBias, 3, hi);
        f32x16 accA[2], accB[2];

        // ---- staggered pipeline: MFMA(tile X) adjacent to independent transition(tile Y) ----
        __builtin_amdgcn_s_setprio(1);
        accA[0] = __builtin_amdgcn_mfma_f32_32x32x16_bf16(L1A[0].v, B1a.v, zero16, 0, 0, 0);
        accA[1] = __builtin_amdgcn_mfma_f32_32x32x16_bf16(L1A[1].v, B1a.v, zero16, 0, 0, 0);
        accB[0] = __builtin_amdgcn_mfma_f32_32x32x16_bf16(L1A[0].v, B1b.v, zero16, 0, 0, 0);
        accB[1] = __builtin_amdgcn_mfma_f32_32x32x16_bf16(L1A[1].v, B1b.v, zero16, 0, 0, 0);
        __builtin_amdgcn_s_setprio(0);

        Frag BhiA[4], BloA[4], BhiB[4], BloB[4];
        transitionHL(accA, br3, BhiA, BloA);              // A: sin after L1
        layerHL(accA, BhiA, BloA, ldsAhi, ldsAlo, 0, lane, zero16);   // A: L0 MFMAs
        transitionHL(accB, br3, BhiB, BloB);              //   ∥ B: sin after L1 (indep)
        layerHL(accB, BhiB, BloB, ldsAhi, ldsAlo, 0, lane, zero16);   // B: L0 MFMAs
        BiasRegs br0 = load_bias(ldsBias, 0, hi);
        transitionHL(accA, br0, BhiA, BloA);              //   ∥ A: sin after L0 (indep)
        layerHL(accA, BhiA, BloA, ldsAhi, ldsAlo, 1, lane, zero16);   // A: L1m MFMAs
        transitionHL(accB, br0, BhiB, BloB);              //   ∥ B: sin after L0
        layerHL(accB, BhiB, BloB, ldsAhi, ldsAlo, 1, lane, zero16);   // B: L1m MFMAs
        BiasRegs br1 = load_bias(ldsBias, 1, hi);
        transitionH(accA, br1, BhiA);                     //   ∥ A: sin after L1m (hi-only)
        layerH(accA, BhiA, ldsAhi, 2, lane, zero16);      // A: L2 MFMAs
        transitionH(accB, br1, BhiB);                     //   ∥ B: sin after L1m
        layerH(accB, BhiB, ldsAhi, 2, lane, zero16);      // B: L2 MFMAs

        // ---- last layer: bias-add + packed f32 sin + dot with LDS-broadcast Wl ----
        BiasRegs br2 = load_bias(ldsBias, 2, hi);
        const f32x2* wl2 = (const f32x2*)&ldsWl[hi][0];
        f32x2 sa = {0.f, 0.f}, sb = {0.f, 0.f};
#pragma unroll
        for (int tg = 0; tg < 2; ++tg)
#pragma unroll
            for (int j = 0; j < 8; ++j) {
                f32x2 w = wl2[tg*8 + j];
                f32x2 za = (f32x2){ accA[tg][2*j], accA[tg][2*j+1] } + br2.p[tg][j];
                f32x2 zb = (f32x2){ accB[tg][2*j], accB[tg][2*j+1] } + br2.p[tg][j];
                sa = __builtin_elementwise_fma(sin2(za), w, sa);
                sb = __builtin_elementwise_fma(sin2(zb), w, sb);
            }
        float suma = sa.x + sa.y;
        float sumb = sb.x + sb.y;
        suma += __shfl_xor(suma, 32);
        sumb += __shfl_xor(sumb, 32);
        if (lane < 32) {
            out[(size_t)ppa*16 + o] = suma + blv;
            out[(size_t)ppb*16 + o] = sumb + blv;
        }
    }
}

extern "C" void kernel_launch(void* const* d_in, const int* in_sizes, int n_in,
                              void* d_out, int out_size, void* d_ws, size_t ws_size,
                              hipStream_t stream) {
    (void)in_sizes; (void)n_in; (void)out_size; (void)d_ws; (void)ws_size;
    siren_kernel<<<dim3(NBGROUPS, 16), dim3(256), 0, stream>>>(
        (const float*)d_in[0], (const float*)d_in[1], (const float*)d_in[2],
        (const float*)d_in[3], (const float*)d_in[4], (const float*)d_in[5],
        (const float*)d_in[6], (float*)d_out);
}

// Round 11
// 357.755 us; speedup vs baseline: 1.0319x; 1.0319x over previous
//
#include <hip/hip_runtime.h>

typedef short bf16x8 __attribute__((ext_vector_type(8)));
typedef float f32x16 __attribute__((ext_vector_type(16)));
typedef float f32x2  __attribute__((ext_vector_type(2)));

#define NBGROUPS 64          // grid = 64 x 16 = 1024 blocks (512 thr); 2 blocks/CU => 2 exact rounds
#define SCALE 4.7746482927568601f   // 30/(2*pi): weights pre-scaled -> args in revolutions

union Frag { bf16x8 v; unsigned u[4]; uint4 q; };

__device__ __forceinline__ unsigned pk_bf16(float lo, float hi) {
    unsigned r;
    asm("v_cvt_pk_bf16_f32 %0, %1, %2" : "=v"(r) : "v"(lo), "v"(hi));
    return r;
}
__device__ __forceinline__ float lo_f(unsigned w) { return __uint_as_float(w << 16); }
__device__ __forceinline__ float hi_f(unsigned w) { return __uint_as_float(w & 0xffff0000u); }

// packed sin(2*pi*z): v = z - rndne(z) in [-0.5,0.5], deg-9 poly (max err ~6e-6)
__device__ __forceinline__ f32x2 sin2(f32x2 z) {
    f32x2 r  = { rintf(z.x), rintf(z.y) };
    f32x2 v  = z - r;
    f32x2 v2 = v * v;
    f32x2 p  = { 32.765379f, 32.765379f };
    p = __builtin_elementwise_fma(p, v2, (f32x2){-74.468884f, -74.468884f});
    p = __builtin_elementwise_fma(p, v2, (f32x2){ 81.365064f,  81.365064f});
    p = __builtin_elementwise_fma(p, v2, (f32x2){-41.331084f, -41.331084f});
    p = __builtin_elementwise_fma(p, v2, (f32x2){  6.2830526f,  6.2830526f});
    return p * v;
}

// Bias table (mid layers 0..2 only): [ ((Lb*2+tg)*2 + hi)*4 + q ] float4.
struct BiasRegs { f32x2 p[2][8]; };
__device__ __forceinline__ BiasRegs load_bias(const float4* ldsBias, int Lb, int hi) {
    BiasRegs br;
#pragma unroll
    for (int tg = 0; tg < 2; ++tg) {
        const float4* base = &ldsBias[((Lb*2+tg)*2 + hi)*4];
#pragma unroll
        for (int q = 0; q < 4; ++q) {
            float4 b = base[q];
            br.p[tg][2*q]   = (f32x2){b.x, b.y};
            br.p[tg][2*q+1] = (f32x2){b.z, b.w};
        }
    }
    return br;
}

// acc -> sin -> hi/lo bf16 B-frags (no bias: first layer folds bias into MFMA)
__device__ __forceinline__ void transition0HL(const f32x16* acc, Frag* Bhi, Frag* Blo) {
#pragma unroll
    for (int tg = 0; tg < 2; ++tg)
#pragma unroll
        for (int j = 0; j < 8; ++j) {
            f32x2 z = { acc[tg][2*j], acc[tg][2*j+1] };
            f32x2 s = sin2(z);
            unsigned ph = pk_bf16(s.x, s.y);
            f32x2 hf = { lo_f(ph), hi_f(ph) };
            f32x2 d  = s - hf;
            Bhi[tg*2 + (j>>2)].u[j&3] = ph;
            Blo[tg*2 + (j>>2)].u[j&3] = pk_bf16(d.x, d.y);
        }
}
// acc + bias -> sin -> hi/lo bf16 B-frags
__device__ __forceinline__ void transitionHL(const f32x16* acc, const BiasRegs& br,
                                             Frag* Bhi, Frag* Blo) {
#pragma unroll
    for (int tg = 0; tg < 2; ++tg)
#pragma unroll
        for (int j = 0; j < 8; ++j) {
            f32x2 z = (f32x2){ acc[tg][2*j], acc[tg][2*j+1] } + br.p[tg][j];
            f32x2 s = sin2(z);
            unsigned ph = pk_bf16(s.x, s.y);
            f32x2 hf = { lo_f(ph), hi_f(ph) };
            f32x2 d  = s - hf;
            Bhi[tg*2 + (j>>2)].u[j&3] = ph;
            Blo[tg*2 + (j>>2)].u[j&3] = pk_bf16(d.x, d.y);
        }
}
// hi-only (feeds the uncompensated last hidden layer)
__device__ __forceinline__ void transitionH(const f32x16* acc, const BiasRegs& br, Frag* Bhi) {
#pragma unroll
    for (int tg = 0; tg < 2; ++tg)
#pragma unroll
        for (int j = 0; j < 8; ++j) {
            f32x2 z = (f32x2){ acc[tg][2*j], acc[tg][2*j+1] } + br.p[tg][j];
            f32x2 s = sin2(z);
            Bhi[tg*2 + (j>>2)].u[j&3] = pk_bf16(s.x, s.y);
        }
}

// one compensated mid-layer MFMA cluster (12 MFMAs)
__device__ __forceinline__ void layerHL(f32x16* acc, const Frag* Bhi, const Frag* Blo,
                                        const uint4* ldsAhi, const uint4* ldsAlo,
                                        int L, int lane, const f32x16& zero16) {
#pragma unroll
    for (int c = 0; c < 4; ++c) {
        Frag Ah0, Ah1, Al0, Al1;
        Ah0.q = ldsAhi[((L*2+0)*4+c)*64 + lane];
        Ah1.q = ldsAhi[((L*2+1)*4+c)*64 + lane];
        Al0.q = ldsAlo[((L*2+0)*4+c)*64 + lane];
        Al1.q = ldsAlo[((L*2+1)*4+c)*64 + lane];
        acc[0] = __builtin_amdgcn_mfma_f32_32x32x16_bf16(Ah0.v, Bhi[c].v, (c==0)?zero16:acc[0], 0, 0, 0);
        acc[1] = __builtin_amdgcn_mfma_f32_32x32x16_bf16(Ah1.v, Bhi[c].v, (c==0)?zero16:acc[1], 0, 0, 0);
        acc[0] = __builtin_amdgcn_mfma_f32_32x32x16_bf16(Ah0.v, Blo[c].v, acc[0], 0, 0, 0);
        acc[1] = __builtin_amdgcn_mfma_f32_32x32x16_bf16(Ah1.v, Blo[c].v, acc[1], 0, 0, 0);
        acc[0] = __builtin_amdgcn_mfma_f32_32x32x16_bf16(Al0.v, Bhi[c].v, acc[0], 0, 0, 0);
        acc[1] = __builtin_amdgcn_mfma_f32_32x32x16_bf16(Al1.v, Bhi[c].v, acc[1], 0, 0, 0);
    }
}
// hi-only last hidden layer (8 MFMAs)
__device__ __forceinline__ void layerH(f32x16* acc, const Frag* Bhi,
                                       const uint4* ldsAhi, int L, int lane,
                                       const f32x16& zero16) {
#pragma unroll
    for (int c = 0; c < 4; ++c) {
        Frag Ah0, Ah1;
        Ah0.q = ldsAhi[((L*2+0)*4+c)*64 + lane];
        Ah1.q = ldsAhi[((L*2+1)*4+c)*64 + lane];
        acc[0] = __builtin_amdgcn_mfma_f32_32x32x16_bf16(Ah0.v, Bhi[c].v, (c==0)?zero16:acc[0], 0, 0, 0);
        acc[1] = __builtin_amdgcn_mfma_f32_32x32x16_bf16(Ah1.v, Bhi[c].v, (c==0)?zero16:acc[1], 0, 0, 0);
    }
}

__global__ __launch_bounds__(512, 4)
void siren_kernel(const float* __restrict__ x, const float* __restrict__ W0m,
                  const float* __restrict__ b0, const float* __restrict__ Wm,
                  const float* __restrict__ bm, const float* __restrict__ Wl,
                  const float* __restrict__ bl, float* __restrict__ out)
{
    __shared__ uint4  ldsAhi[3*2*4*64];   // 24KB: hi frags, layers 0..2
    __shared__ uint4  ldsAlo[2*2*4*64];   // 16KB: lo frags, layers 0..1 only
    __shared__ float4 ldsBias[3*2*2*4];   // 768B: mid-layer biases only
    __shared__ float  ldsWl[2][32];       // 256B: Wl in acc-slot order per half

    const int tid  = threadIdx.x;
    const int pg   = blockIdx.x;          // point group (0..63) — fast dim
    const int o    = blockIdx.y;          // subnet (0..15)
    const int lane = tid & 63;
    const int wv   = tid >> 6;            // 0..7
    const int col  = lane & 31;
    const int hi   = lane >> 5;

    // ---- stage mid-layer weight fragments, hi/lo compensated, pre-scaled ----
    for (int idx = tid; idx < 3*2*4*64; idx += 512) {
        int l2  = idx & 63;
        int fi  = idx >> 6;
        int c   = fi & 3;
        int tg  = (fi >> 2) & 1;
        int L   = fi >> 3;
        int hi2 = l2 >> 5;
        int g   = tg*32 + (l2 & 31);
        int th  = c >> 1, s = c & 1;
        const float2* Wrow2 = (const float2*)(Wm + (((size_t)(L*16 + o)*64 + g)*64));
        uint4 whi, wlo;
        unsigned* uh = (unsigned*)&whi;
        unsigned* ul = (unsigned*)&wlo;
#pragma unroll
        for (int wi = 0; wi < 4; ++wi) {
            int h = th*32 + s*16 + 8*(wi>>1) + 2*(wi&1) + 4*hi2;   // even
            float2 wp = Wrow2[h >> 1];
            float a = SCALE*wp.x, b = SCALE*wp.y;
            unsigned ph = pk_bf16(a, b);
            uh[wi] = ph;
            ul[wi] = pk_bf16(a - lo_f(ph), b - hi_f(ph));
        }
        ldsAhi[idx] = whi;
        if (idx < 2*2*4*64) ldsAlo[idx] = wlo;   // lo only for L=0,1
    }
    // ---- stage mid-layer biases (pre-scaled), contiguous per (Lb,tg,hi) ----
    if (tid < 48) {
        int q   = tid & 3;
        int hi2 = (tid >> 2) & 1;
        int tg  = (tid >> 3) & 1;
        int Lb  = tid >> 4;          // 0..2
        int h0  = tg*32 + 8*q + 4*hi2;
        const float* bsrc = bm + (Lb*16 + o)*64;
        ldsBias[tid] = make_float4(SCALE*bsrc[h0], SCALE*bsrc[h0+1],
                                   SCALE*bsrc[h0+2], SCALE*bsrc[h0+3]);
    }
    // ---- stage last-layer weights in acc-slot order: ldsWl[hi][tg*16+r] ----
    if (tid >= 64 && tid < 128) {
        int t2  = tid - 64;
        int hi2 = t2 >> 5;
        int idx = t2 & 31;
        int tg  = idx >> 4;
        int r   = idx & 15;
        int s = r >> 3, j = r & 7;
        int h = tg*32 + 16*s + (j & 3) + 8*(j >> 2) + 4*hi2;
        ldsWl[hi2][idx] = Wl[o*64 + h];
    }

    // ---- first-layer A frags, compensated, bias folded into k-slots 6,7 ----
    // k-pairs (per lo half): u0:(w0h,w0h)x(x0h,x0l)  u1:(w0l,w1h)x(x0h,x1h)
    //                        u2:(w1h,w1l)x(x1l,x1h)  u3:(bh,bl)x(1,1)
    Frag L1A[2];
#pragma unroll
    for (int tg = 0; tg < 2; ++tg) {
        int g = tg*32 + col;
        float2 wp = ((const float2*)W0m)[o*64 + g];
        float s0 = SCALE*wp.x, s1 = SCALE*wp.y;
        float bias = SCALE*b0[o*64 + g];
        unsigned u0 = pk_bf16(s0, s0);
        float w0h = lo_f(u0);
        float w0l = s0 - w0h;
        unsigned t1 = pk_bf16(s1, s1);
        float w1h = lo_f(t1);
        float w1l = s1 - w1h;
        unsigned ub = pk_bf16(bias, 0.f);
        float bh = lo_f(ub), bl = bias - bh;
        L1A[tg].u[0] = hi ? 0u : u0;
        L1A[tg].u[1] = hi ? 0u : pk_bf16(w0l, w1h);
        L1A[tg].u[2] = hi ? 0u : pk_bf16(w1h, w1l);
        L1A[tg].u[3] = hi ? 0u : pk_bf16(bh, bl);
    }
    const float blv = bl[o] + 0.5f;

    // persistent zero accumulator: C-operand for each chain's first MFMA
    f32x16 zero16;
#pragma unroll
    for (int i = 0; i < 16; ++i) zero16[i] = 0.f;

    __syncthreads();

#pragma unroll 1
    for (int it = 0; it < 16; ++it) {
        const int t  = pg*128 + it*8 + wv;
        const int pp = t*32 + col;

        // ---- first layer B (all lanes; hi-half A is zeroed so no B mask needed) ----
        float2 xv = ((const float2*)x)[pp];
        Frag B1;
        {
            unsigned u0 = pk_bf16(xv.x, xv.x);
            float x0h = lo_f(u0), x0l = xv.x - x0h;
            unsigned u1 = pk_bf16(xv.y, xv.y);
            float x1h = lo_f(u1), x1l = xv.y - x1h;
            B1.u[0] = pk_bf16(x0h, x0l);
            B1.u[1] = pk_bf16(x0h, x1h);
            B1.u[2] = pk_bf16(x1l, x1h);
            B1.u[3] = 0x3f803f80u;   // (1.0, 1.0) bf16
        }

        f32x16 acc[2];
        acc[0] = __builtin_amdgcn_mfma_f32_32x32x16_bf16(L1A[0].v, B1.v, zero16, 0, 0, 0);
        acc[1] = __builtin_amdgcn_mfma_f32_32x32x16_bf16(L1A[1].v, B1.v, zero16, 0, 0, 0);

        Frag Bhi[4], Blo[4];
        transition0HL(acc, Bhi, Blo);                       // bias already in acc
        layerHL(acc, Bhi, Blo, ldsAhi, ldsAlo, 0, lane, zero16);
        BiasRegs br0 = load_bias(ldsBias, 0, hi);
        transitionHL(acc, br0, Bhi, Blo);
        layerHL(acc, Bhi, Blo, ldsAhi, ldsAlo, 1, lane, zero16);
        BiasRegs br1 = load_bias(ldsBias, 1, hi);
        transitionH(acc, br1, Bhi);
        layerH(acc, Bhi, ldsAhi, 2, lane, zero16);

        // ---- last layer: bias-add + packed f32 sin + dot with LDS-broadcast Wl ----
        BiasRegs br2 = load_bias(ldsBias, 2, hi);
        const f32x2* wl2 = (const f32x2*)&ldsWl[hi][0];
        f32x2 sa = {0.f, 0.f};
#pragma unroll
        for (int tg = 0; tg < 2; ++tg)
#pragma unroll
            for (int j = 0; j < 8; ++j) {
                f32x2 w = wl2[tg*8 + j];
                f32x2 za = (f32x2){ acc[tg][2*j], acc[tg][2*j+1] } + br2.p[tg][j];
                sa = __builtin_elementwise_fma(sin2(za), w, sa);
            }
        float suma = sa.x + sa.y;
        suma += __shfl_xor(suma, 32);
        if (lane < 32) out[(size_t)pp*16 + o] = suma + blv;
    }
}

extern "C" void kernel_launch(void* const* d_in, const int* in_sizes, int n_in,
                              void* d_out, int out_size, void* d_ws, size_t ws_size,
                              hipStream_t stream) {
    (void)in_sizes; (void)n_in; (void)out_size; (void)d_ws; (void)ws_size;
    siren_kernel<<<dim3(NBGROUPS, 16), dim3(512), 0, stream>>>(
        (const float*)d_in[0], (const float*)d_in[1], (const float*)d_in[2],
        (const float*)d_in[3], (const float*)d_in[4], (const float*)d_in[5],
        (const float*)d_in[6], (float*)d_out);
}

// Round 14
// 354.577 us; speedup vs baseline: 1.0411x; 1.0090x over previous
//
#include <hip/hip_runtime.h>

typedef float    f32x4 __attribute__((ext_vector_type(4)));
typedef float    f32x2 __attribute__((ext_vector_type(2)));
typedef unsigned u32x4 __attribute__((ext_vector_type(4)));

#define NBGROUPS 64          // grid = 64 x 16 = 1024 blocks (512 thr); 2 blocks/CU, 2 exact rounds
#define SCALE 4.7746482927568601f   // 30/(2*pi): weights pre-scaled -> args in revolutions

union Frag { unsigned u[4]; u32x4 q; };

// All-arch-VGPR MFMA (16x16x32, D==C accumulate). All operands are ext_vector tuples
// (HIP uint4/float4 structs lower as indirect asm operands and fail — must be ext_vector).
__device__ __forceinline__ void mfma16(f32x4& d, u32x4 a, u32x4 b) {
    asm("v_mfma_f32_16x16x32_bf16 %0, %1, %2, %0" : "+v"(d) : "v"(a), "v"(b));
}
__device__ __forceinline__ unsigned pk_bf16(float lo, float hi) {
    unsigned r;
    asm("v_cvt_pk_bf16_f32 %0, %1, %2" : "=v"(r) : "v"(lo), "v"(hi));
    return r;
}
__device__ __forceinline__ float lo_f(unsigned w) { return __uint_as_float(w << 16); }
__device__ __forceinline__ float hi_f(unsigned w) { return __uint_as_float(w & 0xffff0000u); }

// packed sin(2*pi*z): v = z - rndne(z) in [-0.5,0.5], deg-9 poly (max err ~6e-6)
__device__ __forceinline__ f32x2 sin2(f32x2 z) {
    f32x2 r  = { rintf(z.x), rintf(z.y) };
    f32x2 v  = z - r;
    f32x2 v2 = v * v;
    f32x2 p  = { 32.765379f, 32.765379f };
    p = __builtin_elementwise_fma(p, v2, (f32x2){-74.468884f, -74.468884f});
    p = __builtin_elementwise_fma(p, v2, (f32x2){ 81.365064f,  81.365064f});
    p = __builtin_elementwise_fma(p, v2, (f32x2){-41.331084f, -41.331084f});
    p = __builtin_elementwise_fma(p, v2, (f32x2){  6.2830526f,  6.2830526f});
    return p * v;
}

// Bias table: f32x4 per (Lb, t, g2): value = b[16t + 4*g2 .. +3]
__device__ __forceinline__ f32x4 bias_c(const f32x4* ldsBias, int Lb, int t, int g2) {
    return ldsBias[(Lb*4 + t)*4 + g2];
}

// acc (4 tiles, D rows h=16t+4g2+j) -> sin -> hi/lo bf16 B-frags.
// B k-slot map (self-consistent with A staging): chunk m, word w=2s+jp, half p:
//   k = 32m + 16s + 4*g2 + 2*jp + p   (t = 2m+s)
__device__ __forceinline__ void transHL(const f32x4* acc, Frag* Bhi, Frag* Blo) {
#pragma unroll
    for (int m = 0; m < 2; ++m)
#pragma unroll
        for (int s = 0; s < 2; ++s) {
            const int t = 2*m + s;
#pragma unroll
            for (int jp = 0; jp < 2; ++jp) {
                f32x2 z = { acc[t][2*jp], acc[t][2*jp+1] };
                f32x2 sv = sin2(z);
                unsigned ph = pk_bf16(sv.x, sv.y);
                f32x2 hf = { lo_f(ph), hi_f(ph) };
                f32x2 d  = sv - hf;
                Bhi[m].u[2*s+jp] = ph;
                Blo[m].u[2*s+jp] = pk_bf16(d.x, d.y);
            }
        }
}
// hi-only (feeds the uncompensated last hidden layer)
__device__ __forceinline__ void transH(const f32x4* acc, Frag* Bhi) {
#pragma unroll
    for (int m = 0; m < 2; ++m)
#pragma unroll
        for (int s = 0; s < 2; ++s) {
            const int t = 2*m + s;
#pragma unroll
            for (int jp = 0; jp < 2; ++jp) {
                f32x2 z = { acc[t][2*jp], acc[t][2*jp+1] };
                f32x2 sv = sin2(z);
                Bhi[m].u[2*s+jp] = pk_bf16(sv.x, sv.y);
            }
        }
}

// compensated mid-layer cluster: 48 MFMAs, A/B col-groups interleaved (hazard cover + ILP)
__device__ __forceinline__ void layerHL(f32x4* accA, f32x4* accB,
        const Frag* BhiA, const Frag* BloA, const Frag* BhiB, const Frag* BloB,
        const u32x4* ldsAhi, const u32x4* ldsAlo, int L, int lane) {
#pragma unroll
    for (int m = 0; m < 2; ++m)
#pragma unroll
        for (int t = 0; t < 4; ++t) {
            u32x4 Ah = ldsAhi[((L*4+t)*2+m)*64 + lane];
            u32x4 Al = ldsAlo[((L*4+t)*2+m)*64 + lane];
            mfma16(accA[t], Ah, BhiA[m].q);
            mfma16(accB[t], Ah, BhiB[m].q);
            mfma16(accA[t], Ah, BloA[m].q);
            mfma16(accB[t], Ah, BloB[m].q);
            mfma16(accA[t], Al, BhiA[m].q);
            mfma16(accB[t], Al, BhiB[m].q);
        }
}
// hi-only last hidden layer (16 MFMAs)
__device__ __forceinline__ void layerH(f32x4* accA, f32x4* accB,
        const Frag* BhiA, const Frag* BhiB,
        const u32x4* ldsAhi, int L, int lane) {
#pragma unroll
    for (int m = 0; m < 2; ++m)
#pragma unroll
        for (int t = 0; t < 4; ++t) {
            u32x4 Ah = ldsAhi[((L*4+t)*2+m)*64 + lane];
            mfma16(accA[t], Ah, BhiA[m].q);
            mfma16(accB[t], Ah, BhiB[m].q);
        }
}

__global__ __launch_bounds__(512, 4)
void siren_kernel(const float* __restrict__ x, const float* __restrict__ W0m,
                  const float* __restrict__ b0, const float* __restrict__ Wm,
                  const float* __restrict__ bm, const float* __restrict__ Wl,
                  const float* __restrict__ bl, float* __restrict__ out)
{
    __shared__ u32x4 ldsAhi[3*4*2*64];   // 24KB: hi frags [L][t][m][lane], layers 0..2
    __shared__ u32x4 ldsAlo[2*4*2*64];   // 16KB: lo frags, layers 0..1 only
    __shared__ f32x4 ldsBias[4*4*4];     // 1KB: [Lb][t][g2]
    __shared__ float ldsWl[4][16];       // 256B: [g2][t*4+j] = Wl[16t+4g2+j]

    const int tid  = threadIdx.x;
    const int pg   = blockIdx.x;          // point group (0..63)
    const int o    = blockIdx.y;          // subnet (0..15)
    const int lane = tid & 63;
    const int wv   = tid >> 6;            // 0..7
    const int pl   = lane & 15;
    const int g2   = lane >> 4;

    // ---- stage mid-layer weight fragments, hi/lo compensated, pre-scaled ----
    for (int idx = tid; idx < 3*4*2*64; idx += 512) {
        int l2 = idx & 63;
        int fi = idx >> 6;                 // 0..23
        int m  = fi & 1;
        int t  = (fi >> 1) & 3;
        int L  = fi >> 3;                  // 0..2
        int g  = 16*t + (l2 & 15);
        int gg = l2 >> 4;
        const float2* Wrow2 = (const float2*)(Wm + (((size_t)(L*16 + o)*64 + g)*64));
        u32x4 whi, wlo;
        unsigned* uh = (unsigned*)&whi;
        unsigned* ul = (unsigned*)&wlo;
#pragma unroll
        for (int w = 0; w < 4; ++w) {
            int s  = w >> 1, jp = (w & 1) * 2;
            int k  = 32*m + 16*s + 4*gg + jp;    // even
            float2 wp = Wrow2[k >> 1];
            float a = SCALE*wp.x, b = SCALE*wp.y;
            unsigned ph = pk_bf16(a, b);
            uh[w] = ph;
            ul[w] = pk_bf16(a - lo_f(ph), b - hi_f(ph));
        }
        ldsAhi[idx] = whi;
        if (idx < 2*4*2*64) ldsAlo[idx] = wlo;   // lo only for L=0,1
    }
    // ---- stage biases (pre-scaled): [Lb][t][g2] ----
    if (tid < 64) {
        int gg = tid & 3;
        int t  = (tid >> 2) & 3;
        int Lb = tid >> 4;           // 0..2 mid, 3 = first layer
        int h0 = 16*t + 4*gg;
        const float* bsrc = (Lb < 3) ? (bm + (Lb*16 + o)*64) : (b0 + o*64);
        ldsBias[tid] = (f32x4){SCALE*bsrc[h0], SCALE*bsrc[h0+1],
                               SCALE*bsrc[h0+2], SCALE*bsrc[h0+3]};
    }
    // ---- stage last-layer weights: ldsWl[g2][t*4+j] = Wl[16t+4g2+j] ----
    if (tid >= 64 && tid < 128) {
        int t2  = tid - 64;
        int gg  = t2 >> 4;
        int idx = t2 & 15;
        int t   = idx >> 2;
        int j   = idx & 3;
        ldsWl[gg][idx] = Wl[o*64 + 16*t + 4*gg + j];
    }

    // ---- first-layer A frags, fully compensated, lane-group 0 only ----
    // words: u0=(w0h,w0h) u1=(w0l,w1h) u2=(w1h,w1l) u3=0 ; pairs with B1 slots below
    Frag L1A[4];
#pragma unroll
    for (int t = 0; t < 4; ++t) {
        int g = 16*t + pl;
        float2 wp = ((const float2*)W0m)[o*64 + g];
        float s0 = SCALE*wp.x, s1 = SCALE*wp.y;
        unsigned u0 = pk_bf16(s0, s0);
        float w0h = lo_f(u0), w0l = s0 - w0h;
        unsigned u1 = pk_bf16(s1, s1);
        float w1h = lo_f(u1), w1l = s1 - w1h;
        bool zz = (g2 != 0);
        L1A[t].u[0] = zz ? 0u : u0;
        L1A[t].u[1] = zz ? 0u : pk_bf16(w0l, w1h);
        L1A[t].u[2] = zz ? 0u : pk_bf16(w1h, w1l);
        L1A[t].u[3] = 0u;
    }
    const float blv = bl[o] + 0.5f;

    __syncthreads();

#pragma unroll 1
    for (int it = 0; it < 16; ++it) {
        const int t32 = pg*128 + it*8 + wv;
        const int pb  = t32*32;

        // ---- first-layer B: x split hi/lo (exact); words u0=(x0h,x0l) u1=(x0h,x1h) u2=(x1l,x1h) ----
        float2 xa = ((const float2*)x)[pb + pl];
        float2 xb = ((const float2*)x)[pb + 16 + pl];
        Frag B1a, B1b;
        {
            unsigned u0 = pk_bf16(xa.x, xa.x);
            float x0h = lo_f(u0), x0l = xa.x - x0h;
            unsigned u1 = pk_bf16(xa.y, xa.y);
            float x1h = lo_f(u1), x1l = xa.y - x1h;
            B1a.u[0] = pk_bf16(x0h, x0l);
            B1a.u[1] = pk_bf16(x0h, x1h);
            B1a.u[2] = pk_bf16(x1l, x1h);
            B1a.u[3] = 0u;
            u0 = pk_bf16(xb.x, xb.x); x0h = lo_f(u0); x0l = xb.x - x0h;
            u1 = pk_bf16(xb.y, xb.y); x1h = lo_f(u1); x1l = xb.y - x1h;
            B1b.u[0] = pk_bf16(x0h, x0l);
            B1b.u[1] = pk_bf16(x0h, x1h);
            B1b.u[2] = pk_bf16(x1l, x1h);
            B1b.u[3] = 0u;
        }

        f32x4 accA[4], accB[4];
#pragma unroll
        for (int t = 0; t < 4; ++t) {
            accA[t] = bias_c(ldsBias, 3, t, g2);
            accB[t] = bias_c(ldsBias, 3, t, g2);
        }
#pragma unroll
        for (int t = 0; t < 4; ++t) mfma16(accA[t], L1A[t].q, B1a.q);
#pragma unroll
        for (int t = 0; t < 4; ++t) mfma16(accB[t], L1A[t].q, B1b.q);

        Frag BhiA[2], BloA[2], BhiB[2], BloB[2];
        transHL(accA, BhiA, BloA);
        transHL(accB, BhiB, BloB);

        // ---- mid layer 0 (3-term) ----
#pragma unroll
        for (int t = 0; t < 4; ++t) {
            accA[t] = bias_c(ldsBias, 0, t, g2);
            accB[t] = bias_c(ldsBias, 0, t, g2);
        }
        layerHL(accA, accB, BhiA, BloA, BhiB, BloB, ldsAhi, ldsAlo, 0, lane);
        transHL(accA, BhiA, BloA);
        transHL(accB, BhiB, BloB);

        // ---- mid layer 1 (3-term) ----
#pragma unroll
        for (int t = 0; t < 4; ++t) {
            accA[t] = bias_c(ldsBias, 1, t, g2);
            accB[t] = bias_c(ldsBias, 1, t, g2);
        }
        layerHL(accA, accB, BhiA, BloA, BhiB, BloB, ldsAhi, ldsAlo, 1, lane);
        transH(accA, BhiA);
        transH(accB, BhiB);

        // ---- mid layer 2 (hi-only; error passes only through final linear dot) ----
#pragma unroll
        for (int t = 0; t < 4; ++t) {
            accA[t] = bias_c(ldsBias, 2, t, g2);
            accB[t] = bias_c(ldsBias, 2, t, g2);
        }
        layerH(accA, accB, BhiA, BhiB, ldsAhi, 2, lane);

        // ---- last layer: packed f32 sin + dot; reduce over 4 lane-groups ----
        const f32x2* wl2 = (const f32x2*)&ldsWl[g2][0];
        f32x2 sa = {0.f, 0.f}, sb = {0.f, 0.f};
#pragma unroll
        for (int t = 0; t < 4; ++t)
#pragma unroll
            for (int jp = 0; jp < 2; ++jp) {
                f32x2 w = wl2[t*2 + jp];
                f32x2 za = { accA[t][2*jp], accA[t][2*jp+1] };
                f32x2 zb = { accB[t][2*jp], accB[t][2*jp+1] };
                sa = __builtin_elementwise_fma(sin2(za), w, sa);
                sb = __builtin_elementwise_fma(sin2(zb), w, sb);
            }
        float suma = sa.x + sa.y;
        float sumb = sb.x + sb.y;
        suma += __shfl_xor(suma, 16);
        suma += __shfl_xor(suma, 32);
        sumb += __shfl_xor(sumb, 16);
        sumb += __shfl_xor(sumb, 32);
        if (lane < 32) {
            float v = (lane < 16 ? suma : sumb) + blv;
            out[(size_t)(pb + lane)*16 + o] = v;
        }
    }
}

extern "C" void kernel_launch(void* const* d_in, const int* in_sizes, int n_in,
                              void* d_out, int out_size, void* d_ws, size_t ws_size,
                              hipStream_t stream) {
    (void)in_sizes; (void)n_in; (void)out_size; (void)d_ws; (void)ws_size;
    siren_kernel<<<dim3(NBGROUPS, 16), dim3(512), 0, stream>>>(
        (const float*)d_in[0], (const float*)d_in[1], (const float*)d_in[2],
        (const float*)d_in[3], (const float*)d_in[4], (const float*)d_in[5],
        (const float*)d_in[6], (float*)d_out);
}